// Round 2
// baseline (111.849 us; speedup 1.0000x reference)
//
#include <hip/hip_runtime.h>

// CRITICAL: hipcc defaults to -ffp-contract=fast-honor-pragmas, and HIP's
// __fmul_rn/__fadd_rn are PLAIN OPERATORS (not contraction barriers like
// CUDA). This pragma guarantees mul/add are not fused into v_fmac/v_pk_fma,
// so our rounding matches numpy's exactly. (R4 proved this: absmax == 0.0.)
#pragma clang fp contract(off)

typedef float v2f __attribute__((ext_vector_type(2)));

// Forced packed fp32 (VOP3P): per-component rounding == scalar v_mul/v_add.
// NOTE (R10 post-mortem): op_sel broadcast variants are ILLEGAL on pk_f32
// (CDNA VOP3P packed-FP32 requires OPSEL==0) — R10's op_sel asm aborted the
// run. Only plain pk ops below.
static __device__ __forceinline__ v2f pk_mul(v2f a, v2f b) {
    v2f d;
    asm("v_pk_mul_f32 %0, %1, %2" : "=v"(d) : "v"(a), "v"(b));
    return d;
}
static __device__ __forceinline__ v2f pk_add(v2f a, v2f b) {
    v2f d;
    asm("v_pk_add_f32 %0, %1, %2" : "=v"(d) : "v"(a), "v"(b));
    return d;
}
static __device__ __forceinline__ float min3f(float a, float b, float c) {
    float d;
    asm("v_min3_f32 %0, %1, %2, %3" : "=v"(d) : "v"(a), "v"(b), "v"(c));
    return d;
}

// Problem constants (from reference): B=4, N=16384, M=4096, D=64
#define MM 4096
#define DD 64
#define BN 65536                  // B*N points
#define FEATS_OFF 0               // feats: BN*DD floats
#define IDS_OFF (BN * DD)         // ids:   BN floats (ints stored as float)
#define PC_OFF (IDS_OFF + BN)     // pc:    BN*3 floats passthrough

#define BLK 512                   // threads per block (8 waves)
#define CC 32                     // lanes per point
#define PP 8                      // points per thread (register tile)
#define PPB 128                   // points per block (BLK*PP/CC)
#define NPAIR (MM / 2)            // 2048 key pairs
#define KIT (MM / (2 * CC))       // 64 main-loop iterations

// NUMERICS (bit-exact vs numpy fp32 replay — verified R4-R8):
//  - keys stored NEGATED+DOUBLED: rn commutes with sign and 2^k scaling, so
//    cross' = ((px*(-2kx) + py*(-2ky)) + pz*(-2kz)) == -2*cross bit-exact,
//    and d2 = (psq + cross') + ksq == (psq - 2*cross) + ksq == ref bits.
//  - all plain rn (contract off); k_sq/p_sq ascending plain; pk per-lane
//    rounding == scalar.
//  - argmin: bd via v_min3 (== sequential strict-'<' min, no NaNs); bk =
//    first iter where bd strictly dropped (later equal values don't
//    overwrite => first-index kept); within-pair even preferred on tie at
//    recovery; lexicographic (d2,id) butterfly across lanes.
//
// STRUCTURE (R11): body is IDENTICAL to the verified R9 kernel (111.3 µs,
// absmax 0.0). The one change: amdgpu_waves_per_eu(4,4). R9's counters
// (VGPR_Count=64, VALUBusy=63% at ~2.3x the hand-counted 17 µs issue floor)
// showed the allocator capped itself at 64 regs chasing 8 waves/EU, while
// LDS (64 KiB/block) pins occupancy at 2 blocks/CU = 4 waves/EU regardless.
// The ~100-reg live set (the {p,p} broadcast pairs alone are 64 VGPRs) got
// rematerialized every k-iteration. min=4 grants the 128-reg budget; max=4
// stops the shrink heuristic. Main loop: 10 issue slots per key-pair per
// point = 5/eval.
__global__ __launch_bounds__(BLK) __attribute__((amdgpu_waves_per_eu(4, 4)))
void quant_embed_kernel(const float* __restrict__ pc,
                        const float* __restrict__ keys,
                        const float* __restrict__ values,
                        float* __restrict__ out)
{
#pragma clang fp contract(off)
    __shared__ float4 skA[NPAIR];  // (-2kx_e, -2kx_o, -2ky_e, -2ky_o) 32 KiB
    __shared__ float4 skB[NPAIR];  // (-2kz_e, -2kz_o,  ksq_e,  ksq_o) 32 KiB

    const int tid = threadIdx.x;

    // Stage key pairs: pair j = keys 2j (f0.x,f0.y,f1.x), 2j+1 (f1.y,f2.x,f2.y).
    #pragma unroll
    for (int i = 0; i < NPAIR / BLK; ++i) {
        const int j = tid + i * BLK;
        const float2 f0 = ((const float2*)keys)[3 * j + 0];
        const float2 f1 = ((const float2*)keys)[3 * j + 1];
        const float2 f2 = ((const float2*)keys)[3 * j + 2];
        const float ksq0 = ((f0.x * f0.x) + (f0.y * f0.y)) + (f1.x * f1.x);
        const float ksq1 = ((f1.y * f1.y) + (f2.x * f2.x)) + (f2.y * f2.y);
        skA[j] = make_float4(-2.0f * f0.x, -2.0f * f1.y,
                             -2.0f * f0.y, -2.0f * f2.x);
        skB[j] = make_float4(-2.0f * f1.x, -2.0f * f2.y, ksq0, ksq1);
    }

    // pc passthrough for this block's 128 points: 384 floats = 96 float4.
    {
        const int base = blockIdx.x * (PPB * 3 / 4);  // in float4
        if (tid < PPB * 3 / 4) {
            ((float4*)(out + PC_OFF))[base + tid] =
                ((const float4*)pc)[base + tid];
        }
    }

    const int c = tid & (CC - 1);
    const int g = tid >> 5;                       // point-group 0..15
    const int p0 = blockIdx.x * PPB + g * PP;     // my first point

    // Load my 8 points (24 floats = 6 float4, aligned: 3*p0 % 4 == 0).
    float arr[24];
    {
        const float4* pcv = (const float4*)(pc + 3 * p0);
        #pragma unroll
        for (int i = 0; i < 6; ++i) ((float4*)arr)[i] = pcv[i];
    }
    v2f PX[PP], PY[PP], PZ[PP], PSQ[PP];
    float bd[PP];
    int bk[PP];
    #pragma unroll
    for (int i = 0; i < PP; ++i) {
        const float px = arr[3 * i + 0];
        const float py = arr[3 * i + 1];
        const float pz = arr[3 * i + 2];
        const float psq = ((px * px) + (py * py)) + (pz * pz);
        PX[i] = (v2f){px, px};
        PY[i] = (v2f){py, py};
        PZ[i] = (v2f){pz, pz};
        PSQ[i] = (v2f){psq, psq};
        bd[i] = 3.402823466e38f;
        bk[i] = 0;
    }

    __syncthreads();

    // Main loop: lane c, iter k handles pair j = 32k + c (keys 64k+2c, +1).
    // Per pair per point: 7 pk + min3 + cmp + cndmask = 10 slots / 2 evals.
    #pragma unroll 2
    for (int k = 0; k < KIT; ++k) {
        const int j = (k << 5) + c;
        const float4 A  = skA[j];
        const float4 Bv = skB[j];
        const v2f Kx = {A.x,  A.y};
        const v2f Ky = {A.z,  A.w};
        const v2f Kz = {Bv.x, Bv.y};
        const v2f Ks = {Bv.z, Bv.w};
        #pragma unroll
        for (int i = 0; i < PP; ++i) {
            v2f t = pk_add(pk_mul(Kx, PX[i]), pk_mul(Ky, PY[i]));
            t = pk_add(t, pk_mul(Kz, PZ[i]));
            t = pk_add(PSQ[i], t);       // psq - 2*cross (keys negated)
            t = pk_add(t, Ks);           // + ksq
            const float nb = min3f(bd[i], t.x, t.y);
            const bool ch = nb < bd[i];  // strict drop => first-index kept
            bd[i] = nb;
            bk[i] = ch ? k : bk[i];
        }
    }

    // Recover the winning key within pair bk[i] (scalar plain == pk bits),
    // then merge the 32 lanes (lexicographic (d2,id) butterfly).
    int bm[PP];
    #pragma unroll
    for (int i = 0; i < PP; ++i) {
        const int j = (bk[i] << 5) + c;
        const float4 A  = skA[j];
        const float4 Bv = skB[j];
        const float ca = ((PX[i].x * A.x) + (PY[i].x * A.z)) + (PZ[i].x * Bv.x);
        const float da = (PSQ[i].x + ca) + Bv.z;
        const int m0 = (bk[i] << 6) + (c << 1);
        float d = bd[i];
        int   m = (da == bd[i]) ? m0 : (m0 + 1);  // even preferred on tie
        #pragma unroll
        for (int off = 1; off < CC; off <<= 1) {
            const float od = __shfl_xor(d, off);
            const int   om = __shfl_xor(m, off);
            if (od < d || (od == d && om < m)) { d = od; m = om; }
        }
        bm[i] = m;
    }

    // Epilogue: each point's 32 lanes copy its 64-float value row
    // (1 float2 per lane, coalesced 256B); lane c==0 writes the id.
    #pragma unroll
    for (int i = 0; i < PP; ++i) {
        const float2* vrow = (const float2*)(values + (size_t)bm[i] * DD);
        ((float2*)(out + FEATS_OFF + (size_t)(p0 + i) * DD))[c] = vrow[c];
        if (c == 0) out[IDS_OFF + p0 + i] = (float)bm[i];
    }
}

extern "C" void kernel_launch(void* const* d_in, const int* in_sizes, int n_in,
                              void* d_out, int out_size, void* d_ws, size_t ws_size,
                              hipStream_t stream) {
    const float* pc     = (const float*)d_in[0];
    const float* keys   = (const float*)d_in[1];
    const float* values = (const float*)d_in[2];
    float* out = (float*)d_out;

    dim3 grid(BN / PPB);  // 512 blocks of 512 threads = 2 blocks/CU
    dim3 block(BLK);
    quant_embed_kernel<<<grid, block, 0, stream>>>(pc, keys, values, out);
}

// Round 3
// 108.300 us; speedup vs baseline: 1.0328x; 1.0328x over previous
//
#include <hip/hip_runtime.h>

// CRITICAL: hipcc defaults to -ffp-contract=fast-honor-pragmas, and HIP's
// __fmul_rn/__fadd_rn are PLAIN OPERATORS (not contraction barriers like
// CUDA). This pragma guarantees mul/add are not fused into v_fmac/v_pk_fma,
// so our rounding matches numpy's exactly. (R4 proved this: absmax == 0.0.)
#pragma clang fp contract(off)

typedef float v2f __attribute__((ext_vector_type(2)));

// Forced packed fp32 (VOP3P): per-component rounding == scalar v_mul/v_add.
// NOTE (R10 post-mortem): op_sel broadcast variants are ILLEGAL on pk_f32
// (CDNA VOP3P packed-FP32 requires OPSEL==0) — R10's op_sel asm aborted the
// run. Only plain pk ops below.
static __device__ __forceinline__ v2f pk_mul(v2f a, v2f b) {
    v2f d;
    asm("v_pk_mul_f32 %0, %1, %2" : "=v"(d) : "v"(a), "v"(b));
    return d;
}
static __device__ __forceinline__ v2f pk_add(v2f a, v2f b) {
    v2f d;
    asm("v_pk_add_f32 %0, %1, %2" : "=v"(d) : "v"(a), "v"(b));
    return d;
}
static __device__ __forceinline__ float min3f(float a, float b, float c) {
    float d;
    asm("v_min3_f32 %0, %1, %2, %3" : "=v"(d) : "v"(a), "v"(b), "v"(c));
    return d;
}

// Problem constants (from reference): B=4, N=16384, M=4096, D=64
#define MM 4096
#define DD 64
#define BN 65536                  // B*N points
#define FEATS_OFF 0               // feats: BN*DD floats
#define IDS_OFF (BN * DD)         // ids:   BN floats (ints stored as float)
#define PC_OFF (IDS_OFF + BN)     // pc:    BN*3 floats passthrough

#define BLK 512                   // threads per block (8 waves)
#define CC 32                     // lanes per point
#define PP 4                      // points per thread (register tile) — R12
#define PPB 64                    // points per block (BLK*PP/CC)
#define NPAIR (MM / 2)            // 2048 key pairs
#define KIT (MM / (2 * CC))       // 64 main-loop iterations

// NUMERICS (bit-exact vs numpy fp32 replay — verified R4-R8):
//  - keys stored NEGATED+DOUBLED: rn commutes with sign and 2^k scaling, so
//    cross' = ((px*(-2kx) + py*(-2ky)) + pz*(-2kz)) == -2*cross bit-exact,
//    and d2 = (psq + cross') + ksq == (psq - 2*cross) + ksq == ref bits.
//  - all plain rn (contract off); k_sq/p_sq ascending plain; pk per-lane
//    rounding == scalar.
//  - argmin: bd via v_min3 (== sequential strict-'<' min, no NaNs); bk =
//    first iter where bd strictly dropped (later equal values don't
//    overwrite => first-index kept); within-pair even preferred on tie at
//    recovery; lexicographic (d2,id) butterfly across lanes.
//
// STRUCTURE (R12): discriminating experiment for the 2.1x VALU-issue bloat
// seen in R9/R11 (94k busy cyc/SIMD vs ~45k hand-counted; VGPR_Count
// pinned at 64 while the PP=8 live set was ~100). The {p,p} broadcast
// pairs (64 VGPRs at PP=8) cannot be register-coalesced, so the compiler
// rebuilds them with v_mov inside the 64-iter k-loop regardless of budget
// knobs (R11 proved waves_per_eu(4,4) is a no-op here). PP=4 halves the
// point state to 32 regs => live set ~66, remat pressure gone. Per-point
// numerics/semantics are untouched; total device work identical
// (10 issue slots per key-pair per point = 5/eval).
__global__ __launch_bounds__(BLK) __attribute__((amdgpu_waves_per_eu(4, 4)))
void quant_embed_kernel(const float* __restrict__ pc,
                        const float* __restrict__ keys,
                        const float* __restrict__ values,
                        float* __restrict__ out)
{
#pragma clang fp contract(off)
    __shared__ float4 skA[NPAIR];  // (-2kx_e, -2kx_o, -2ky_e, -2ky_o) 32 KiB
    __shared__ float4 skB[NPAIR];  // (-2kz_e, -2kz_o,  ksq_e,  ksq_o) 32 KiB

    const int tid = threadIdx.x;

    // Stage key pairs: pair j = keys 2j (f0.x,f0.y,f1.x), 2j+1 (f1.y,f2.x,f2.y).
    #pragma unroll
    for (int i = 0; i < NPAIR / BLK; ++i) {
        const int j = tid + i * BLK;
        const float2 f0 = ((const float2*)keys)[3 * j + 0];
        const float2 f1 = ((const float2*)keys)[3 * j + 1];
        const float2 f2 = ((const float2*)keys)[3 * j + 2];
        const float ksq0 = ((f0.x * f0.x) + (f0.y * f0.y)) + (f1.x * f1.x);
        const float ksq1 = ((f1.y * f1.y) + (f2.x * f2.x)) + (f2.y * f2.y);
        skA[j] = make_float4(-2.0f * f0.x, -2.0f * f1.y,
                             -2.0f * f0.y, -2.0f * f2.x);
        skB[j] = make_float4(-2.0f * f1.x, -2.0f * f2.y, ksq0, ksq1);
    }

    // pc passthrough for this block's 64 points: 192 floats = 48 float4.
    {
        const int base = blockIdx.x * (PPB * 3 / 4);  // in float4
        if (tid < PPB * 3 / 4) {
            ((float4*)(out + PC_OFF))[base + tid] =
                ((const float4*)pc)[base + tid];
        }
    }

    const int c = tid & (CC - 1);
    const int g = tid >> 5;                       // point-group 0..15
    const int p0 = blockIdx.x * PPB + g * PP;     // my first point

    // Load my 4 points (12 floats = 3 float4, aligned: 3*p0 % 4 == 0).
    float arr[12];
    {
        const float4* pcv = (const float4*)(pc + 3 * p0);
        #pragma unroll
        for (int i = 0; i < 3; ++i) ((float4*)arr)[i] = pcv[i];
    }
    v2f PX[PP], PY[PP], PZ[PP], PSQ[PP];
    float bd[PP];
    int bk[PP];
    #pragma unroll
    for (int i = 0; i < PP; ++i) {
        const float px = arr[3 * i + 0];
        const float py = arr[3 * i + 1];
        const float pz = arr[3 * i + 2];
        const float psq = ((px * px) + (py * py)) + (pz * pz);
        PX[i] = (v2f){px, px};
        PY[i] = (v2f){py, py};
        PZ[i] = (v2f){pz, pz};
        PSQ[i] = (v2f){psq, psq};
        bd[i] = 3.402823466e38f;
        bk[i] = 0;
    }

    __syncthreads();

    // Main loop: lane c, iter k handles pair j = 32k + c (keys 64k+2c, +1).
    // Per pair per point: 7 pk + min3 + cmp + cndmask = 10 slots / 2 evals.
    #pragma unroll 2
    for (int k = 0; k < KIT; ++k) {
        const int j = (k << 5) + c;
        const float4 A  = skA[j];
        const float4 Bv = skB[j];
        const v2f Kx = {A.x,  A.y};
        const v2f Ky = {A.z,  A.w};
        const v2f Kz = {Bv.x, Bv.y};
        const v2f Ks = {Bv.z, Bv.w};
        #pragma unroll
        for (int i = 0; i < PP; ++i) {
            v2f t = pk_add(pk_mul(Kx, PX[i]), pk_mul(Ky, PY[i]));
            t = pk_add(t, pk_mul(Kz, PZ[i]));
            t = pk_add(PSQ[i], t);       // psq - 2*cross (keys negated)
            t = pk_add(t, Ks);           // + ksq
            const float nb = min3f(bd[i], t.x, t.y);
            const bool ch = nb < bd[i];  // strict drop => first-index kept
            bd[i] = nb;
            bk[i] = ch ? k : bk[i];
        }
    }

    // Recover the winning key within pair bk[i] (scalar plain == pk bits),
    // then merge the 32 lanes (lexicographic (d2,id) butterfly).
    int bm[PP];
    #pragma unroll
    for (int i = 0; i < PP; ++i) {
        const int j = (bk[i] << 5) + c;
        const float4 A  = skA[j];
        const float4 Bv = skB[j];
        const float ca = ((PX[i].x * A.x) + (PY[i].x * A.z)) + (PZ[i].x * Bv.x);
        const float da = (PSQ[i].x + ca) + Bv.z;
        const int m0 = (bk[i] << 6) + (c << 1);
        float d = bd[i];
        int   m = (da == bd[i]) ? m0 : (m0 + 1);  // even preferred on tie
        #pragma unroll
        for (int off = 1; off < CC; off <<= 1) {
            const float od = __shfl_xor(d, off);
            const int   om = __shfl_xor(m, off);
            if (od < d || (od == d && om < m)) { d = od; m = om; }
        }
        bm[i] = m;
    }

    // Epilogue: each point's 32 lanes copy its 64-float value row
    // (1 float2 per lane, coalesced 256B); lane c==0 writes the id.
    #pragma unroll
    for (int i = 0; i < PP; ++i) {
        const float2* vrow = (const float2*)(values + (size_t)bm[i] * DD);
        ((float2*)(out + FEATS_OFF + (size_t)(p0 + i) * DD))[c] = vrow[c];
        if (c == 0) out[IDS_OFF + p0 + i] = (float)bm[i];
    }
}

extern "C" void kernel_launch(void* const* d_in, const int* in_sizes, int n_in,
                              void* d_out, int out_size, void* d_ws, size_t ws_size,
                              hipStream_t stream) {
    const float* pc     = (const float*)d_in[0];
    const float* keys   = (const float*)d_in[1];
    const float* values = (const float*)d_in[2];
    float* out = (float*)d_out;

    dim3 grid(BN / PPB);  // 1024 blocks of 512 threads (2 resident/CU)
    dim3 block(BLK);
    quant_embed_kernel<<<grid, block, 0, stream>>>(pc, keys, values, out);
}